// Round 2
// baseline (352.076 us; speedup 1.0000x reference)
//
#include <hip/hip_runtime.h>
#include <hip/hip_bf16.h>

#define KNEIGH 16
#define FDIM   128

// One wave (64 lanes) per batch row. Each lane owns a float2 slice of the
// 128-float feature row: 8 B/lane * 64 lanes = 512 B per gathered row,
// a single fully-coalesced transaction per neighbor.
//
// `row` is forced wave-uniform via readfirstlane so the 16 weights and 16
// indices compile to SCALAR loads (s_load) into SGPRs: the 16 gather loads
// then use scalar base addresses (zero per-load VALU addr math, no
// ds_bpermute), minimizing VGPR pressure and letting all 16 loads issue
// back-to-back for full memory-level parallelism.
__global__ __launch_bounds__(256) void WeightedAggregator_89489938580183_kernel(
    const float* __restrict__ features,   // [N, 128]
    const float* __restrict__ neigh_w,    // [B, 16]
    const int*   __restrict__ neigh_idx,  // [B, 16] (int32 per harness)
    float*       __restrict__ out,        // [B, 128]
    int batch) {

    const int lane = threadIdx.x & 63;
    int row = blockIdx.x * 4 + (threadIdx.x >> 6);
    row = __builtin_amdgcn_readfirstlane(row);   // provably wave-uniform
    if (row >= batch) return;

    const float* __restrict__ wp = neigh_w   + (size_t)row * KNEIGH;
    const int*   __restrict__ ip = neigh_idx + (size_t)row * KNEIGH;

    // Wave-uniform scalar reads of the row's weights and indices.
    float w[KNEIGH];
    int   ix[KNEIGH];
    float sum = 0.0f;
    #pragma unroll
    for (int k = 0; k < KNEIGH; ++k) {
        w[k]  = wp[k];
        ix[k] = ip[k];
        sum  += w[k];
    }
    const float inv = 1.0f / sum;

    float2 acc = make_float2(0.0f, 0.0f);
    #pragma unroll
    for (int k = 0; k < KNEIGH; ++k) {
        const float2 f =
            ((const float2*)(features + (size_t)(unsigned)ix[k] * FDIM))[lane];
        const float wk = w[k] * inv;
        acc.x = fmaf(wk, f.x, acc.x);
        acc.y = fmaf(wk, f.y, acc.y);
    }

    ((float2*)(out + (size_t)row * FDIM))[lane] = acc;
}

extern "C" void kernel_launch(void* const* d_in, const int* in_sizes, int n_in,
                              void* d_out, int out_size, void* d_ws, size_t ws_size,
                              hipStream_t stream) {
    const float* features  = (const float*)d_in[0];
    const float* neigh_w   = (const float*)d_in[1];
    const int*   neigh_idx = (const int*)d_in[2];
    float*       out       = (float*)d_out;

    const int batch = in_sizes[1] / KNEIGH;      // 50000

    // 4 waves per 256-thread block, one wave per row.
    const int waves_per_block = 256 / 64;
    const int blocks = (batch + waves_per_block - 1) / waves_per_block;
    WeightedAggregator_89489938580183_kernel<<<blocks, 256, 0, stream>>>(
        features, neigh_w, neigh_idx, out, batch);
}